// Round 20
// baseline (720.513 us; speedup 1.0000x reference)
//
#include <hip/hip_runtime.h>
#include <hip/hip_bf16.h>

// Swin block, MI355X. v20: v19 + attn processes 2 windows/block (grid 1024) to
// halve drain/refill generations; rpb staged once. Everything else identical.
// B=32 H=W=64 C=192 WS=8 SS=4 NH=6 Dh=32; T=131072.

#define DI __device__ __forceinline__

typedef __attribute__((ext_vector_type(8))) short bhalf8;   // 8 bf16 (4 VGPR)
typedef __attribute__((ext_vector_type(4))) float f32x4;
typedef unsigned short u16;
typedef unsigned int   u32;

DI u32 f2bf2(float a, float b){                // pack 2 f32 -> 2 bf16 (1 VALU op)
  u32 r;
  asm("v_cvt_pk_bf16_f32 %0, %1, %2" : "=v"(r) : "v"(a), "v"(b));
  return r;
}
DI u16 f2bf(float f){ return (u16)f2bf2(f, f); }

// gelu ~= x * sigmoid(1.702 x)
DI float fast_gelu(float x){
  float s = __expf(-1.702f * x);
  return x * __builtin_amdgcn_rcpf(1.0f + s);
}

// window-token index t -> global token g (shift+partition map; gather & scatter identical)
DI int tok2glob(int t){
  int n = t & 63, widx = t >> 6;
  int b = widx >> 6, wi = widx & 63;
  int hh = ((wi >> 3) << 3) + (n >> 3);
  int ww = ((wi & 7) << 3) + (n & 7);
  int hs = (hh + 4) & 63, wsv = (ww + 4) & 63;
  return (b << 12) + (hs << 6) + wsv;
}

DI int region_id(int hpos, int wpos){
  int rh = (hpos < 56) ? 0 : ((hpos < 60) ? 1 : 2);
  int rw = (wpos < 56) ? 0 : ((wpos < 60) ? 1 : 2);
  return rh*3 + rw;
}

// ------------- weight prep, all four in one launch -------------
__global__ void transcast_all_kernel(const float* __restrict__ qw, const float* __restrict__ pw,
    const float* __restrict__ f1, const float* __restrict__ f2,
    u16* __restrict__ o0, u16* __restrict__ o1, u16* __restrict__ o2, u16* __restrict__ o3){
  int idx = blockIdx.x * 256 + threadIdx.x;
  const float* W; u16* O; int K, N;
  if (idx < 110592){ W = qw; O = o0; K = 192; N = 576; }
  else if (idx < 147456){ idx -= 110592; W = pw; O = o1; K = 192; N = 192; }
  else if (idx < 294912){ idx -= 147456; W = f1; O = o2; K = 192; N = 768; }
  else if (idx < 442368){ idx -= 294912; W = f2; O = o3; K = 768; N = 192; }
  else return;
  int n = idx / K, k = idx - n*K;
  O[idx] = f2bf(W[(size_t)k * N + n]);
}

// =================== attn_fused: 2 windows / block, 768 threads (12 waves) ===================
__global__ __launch_bounds__(768, 3) void attn_fused_kernel(
    const float* __restrict__ x, const float* __restrict__ n1g, const float* __restrict__ n1b,
    const u16* __restrict__ qkvWt, const float* __restrict__ qkv_b,
    const u16* __restrict__ projWt, const float* __restrict__ proj_b,
    float* __restrict__ out, const float* __restrict__ rpb){
  __shared__ u16 AsB[64*192];      // 24 KB: LN'd tokens; later aliased as Clds
  __shared__ u16 QKB[64*384];      // 48 KB: Q|K tiles; later aliased as P (6 x 64x64)
  __shared__ u16 Vt[6][32*64];     // 24 KB: V^T per head, XOR-swizzled
  __shared__ float Rlds[225*6];
  int tid  = threadIdx.x;
  int w = tid >> 6, lane = tid & 63, lr = lane & 15, lg = lane >> 4;
  int hd   = (w < 6) ? w : (w - 6);
  int half = (w < 6) ? 0 : 1;
  f32x4 zero = (f32x4){0.f,0.f,0.f,0.f};

  if (w >= 8){                     // waves 8-11: stage rel-pos bias (once per block)
    for (int i = tid - 512; i < 225*6; i += 256) Rlds[i] = rpb[i];
  }

  for (int wloop = 0; wloop < 2; wloop++){
    int widx = (blockIdx.x << 1) + wloop;

    if (w < 8){                    // waves 0-7: LN1, 8 threads/row
      int qrow = tid >> 3, oct = tid & 7;
      int g = tok2glob(widx*64 + qrow);
      const float4* xr = (const float4*)(x + (size_t)g*192 + oct*24);
      float4 va[6];
      float s = 0.f, sq = 0.f;
      #pragma unroll
      for (int j = 0; j < 6; j++){
        va[j] = xr[j];
        s  += va[j].x + va[j].y + va[j].z + va[j].w;
        sq += va[j].x*va[j].x + va[j].y*va[j].y + va[j].z*va[j].z + va[j].w*va[j].w;
      }
      s  += __shfl_xor(s, 1, 64);  sq += __shfl_xor(sq, 1, 64);
      s  += __shfl_xor(s, 2, 64);  sq += __shfl_xor(sq, 2, 64);
      s  += __shfl_xor(s, 4, 64);  sq += __shfl_xor(sq, 4, 64);
      float mean = s * (1.f/192.f);
      float rstd = rsqrtf(sq * (1.f/192.f) - mean*mean + 1e-5f);
      const float4* g4 = (const float4*)(n1g + oct*24);
      const float4* b4 = (const float4*)(n1b + oct*24);
      #pragma unroll
      for (int j2 = 0; j2 < 3; j2++){
        float4 v0 = va[2*j2], v1 = va[2*j2+1];
        float4 g0 = g4[2*j2], g1 = g4[2*j2+1];
        float4 b0 = b4[2*j2], b1 = b4[2*j2+1];
        uint4 pk;
        pk.x = f2bf2((v0.x-mean)*rstd*g0.x+b0.x, (v0.y-mean)*rstd*g0.y+b0.y);
        pk.y = f2bf2((v0.z-mean)*rstd*g0.z+b0.z, (v0.w-mean)*rstd*g0.w+b0.w);
        pk.z = f2bf2((v1.x-mean)*rstd*g1.x+b1.x, (v1.y-mean)*rstd*g1.y+b1.y);
        pk.w = f2bf2((v1.z-mean)*rstd*g1.z+b1.z, (v1.w-mean)*rstd*g1.w+b1.w);
        int gk = oct*3 + j2;
        *(uint4*)&AsB[qrow*192 + ((gk ^ (qrow & 7)) << 3)] = pk;
      }
    }
    __syncthreads();               // AsB (+ Rlds on iter 0) ready

    // ---- qkv GEMM: wave w computes output cols [w*48, w*48+48) ----
    #pragma unroll
    for (int nf = 0; nf < 3; nf++){
      int cBase = w*48 + nf*16;
      bhalf8 wF[6];
      #pragma unroll
      for (int kk = 0; kk < 6; kk++)
        wF[kk] = *(const bhalf8*)&qkvWt[(size_t)(cBase + lr)*192 + kk*32 + (lg<<3)];
      float4 bv = *(const float4*)&qkv_b[cBase + (lg<<2)];
      #pragma unroll
      for (int i = 0; i < 4; i++){
        f32x4 a0 = (f32x4){0.f,0.f,0.f,0.f}, a1 = (f32x4){0.f,0.f,0.f,0.f};
        #pragma unroll
        for (int kk = 0; kk < 3; kk++){
          int row = i*16 + lr;
          bhalf8 t0 = *(const bhalf8*)&AsB[row*192 + (((2*kk*4     + lg) ^ (row & 7)) << 3)];
          bhalf8 t1 = *(const bhalf8*)&AsB[row*192 + ((((2*kk+1)*4 + lg) ^ (row & 7)) << 3)];
          a0 = __builtin_amdgcn_mfma_f32_16x16x32_bf16(wF[2*kk],   t0, a0, 0, 0, 0);
          a1 = __builtin_amdgcn_mfma_f32_16x16x32_bf16(wF[2*kk+1], t1, a1, 0, 0, 0);
        }
        float v0 = a0[0]+a1[0]+bv.x, v1 = a0[1]+a1[1]+bv.y;
        float v2 = a0[2]+a1[2]+bv.z, v3 = a0[3]+a1[3]+bv.w;
        int token = i*16 + lr;
        if (cBase < 384){          // Q|K: packed uint2 into swizzled QKB
          int gq = (cBase >> 3) + (lg >> 1);
          uint2 pk; pk.x = f2bf2(v0, v1); pk.y = f2bf2(v2, v3);
          *(uint2*)&QKB[token*384 + ((gq ^ (token & 7)) << 3) + ((lg & 1) << 2)] = pk;
        } else {                   // V: transposed scatter into Vt
          int d0 = cBase + (lg<<2) - 384;
          int hv = d0 >> 5;
          int db = d0 & 31;
          Vt[hv][(db+0)*64 + (token ^ (((db+0)&7)<<3))] = f2bf(v0);
          Vt[hv][(db+1)*64 + (token ^ (((db+1)&7)<<3))] = f2bf(v1);
          Vt[hv][(db+2)*64 + (token ^ (((db+2)&7)<<3))] = f2bf(v2);
          Vt[hv][(db+3)*64 + (token ^ (((db+3)&7)<<3))] = f2bf(v3);
        }
      }
    }
    __syncthreads();               // QKB + Vt complete

    // ---- scores: wave (hd, half) = head hd, q-rows [half*32, half*32+32) ----
    bhalf8 qf[2], kf[4];
    #pragma unroll
    for (int i = 0; i < 2; i++){
      int token = (half*2 + i)*16 + lr;
      int gq = hd*4 + lg;
      qf[i] = *(const bhalf8*)&QKB[token*384 + ((gq ^ (token & 7)) << 3)];
    }
    #pragma unroll
    for (int j = 0; j < 4; j++){
      int token = j*16 + lr;
      int gk = 24 + hd*4 + lg;
      kf[j] = *(const bhalf8*)&QKB[token*384 + ((gk ^ (token & 7)) << 3)];
    }
    f32x4 sc[2][4];
    __builtin_amdgcn_s_setprio(1);
    #pragma unroll
    for (int i = 0; i < 2; i++)
      #pragma unroll
      for (int j = 0; j < 4; j++)
        sc[i][j] = __builtin_amdgcn_mfma_f32_16x16x32_bf16(qf[i], kf[j], zero, 0, 0, 0);
    __builtin_amdgcn_s_setprio(0);

    // prefetch proj weight fragments (hide under softmax+PV; L1-hot on iter 1)
    bhalf8 pw[6][2];
    #pragma unroll
    for (int kk = 0; kk < 6; kk++)
      #pragma unroll
      for (int n = 0; n < 2; n++)
        pw[kk][n] = *(const bhalf8*)&projWt[(size_t)(hd*32 + n*16 + lr)*192 + kk*32 + (lg<<3)];

    __syncthreads();               // all QKB reads done -> safe to overwrite with P

    // ---- softmax (+rel-pos bias +shift mask), P into QKB region ----
    u16* Plds = &QKB[0];
    int mwin = widx >> 5;          // faithful to reference reshape quirk
    int mh0 = (mwin >> 3) << 3, mw0 = (mwin & 7) << 3;
    #pragma unroll
    for (int i = 0; i < 2; i++){
      #pragma unroll
      for (int r = 0; r < 4; r++){
        int row = (half*2 + i)*16 + lg*4 + r;
        int ih = row >> 3, iw = row & 7;
        int ridr = region_id(mh0 + ih, mw0 + iw);
        float vals[4];
        #pragma unroll
        for (int j = 0; j < 4; j++){
          int col = j*16 + lr;
          int jh = col >> 3, jw = col & 7;
          float bias = Rlds[((ih-jh+7)*15 + (iw-jw+7))*6 + hd];
          int ridc = region_id(mh0 + jh, mw0 + jw);
          vals[j] = sc[i][j][r] * 0.17677669529663687f + bias + ((ridr==ridc) ? 0.f : -100.f);
        }
        float mx = fmaxf(fmaxf(vals[0],vals[1]), fmaxf(vals[2],vals[3]));
        #pragma unroll
        for (int d = 1; d < 16; d <<= 1) mx = fmaxf(mx, __shfl_xor(mx, d, 64));
        float sum = 0.f;
        #pragma unroll
        for (int j = 0; j < 4; j++){ vals[j] = __expf(vals[j]-mx); sum += vals[j]; }
        #pragma unroll
        for (int d = 1; d < 16; d <<= 1) sum += __shfl_xor(sum, d, 64);
        float inv = __builtin_amdgcn_rcpf(sum);
        #pragma unroll
        for (int j = 0; j < 4; j++){
          int col = j*16 + lr;
          Plds[hd*4096 + row*64 + (col ^ ((row & 7) << 3))] = f2bf(vals[j]*inv);
        }
      }
    }

    // ---- PV: wave-local P rows + Vt[hd] ----
    f32x4 oa[2][2];
    #pragma unroll
    for (int i=0;i<2;i++)
      #pragma unroll
      for (int n=0;n<2;n++) oa[i][n] = zero;
    #pragma unroll
    for (int kb = 0; kb < 2; kb++){
      bhalf8 pf[2], vf[2];
      int k = (kb<<5) + (lg<<3);
      #pragma unroll
      for (int i = 0; i < 2; i++){
        int row = (half*2 + i)*16 + lr;
        pf[i] = *(const bhalf8*)&Plds[hd*4096 + row*64 + (k ^ ((row&7)<<3))];
      }
      #pragma unroll
      for (int n = 0; n < 2; n++){
        int d = n*16 + lr;
        vf[n] = *(const bhalf8*)&Vt[hd][d*64 + (k ^ ((d&7)<<3))];
      }
      __builtin_amdgcn_s_setprio(1);
      #pragma unroll
      for (int i=0;i<2;i++)
        #pragma unroll
        for (int n=0;n<2;n++)
          oa[i][n] = __builtin_amdgcn_mfma_f32_16x16x32_bf16(pf[i], vf[n], oa[i][n], 0, 0, 0);
      __builtin_amdgcn_s_setprio(0);
    }

    // ---- ctx -> Clds (aliases AsB; AsB dead since qkv barrier) ----
    u16* Clds = &AsB[0];
    #pragma unroll
    for (int i=0;i<2;i++)
      #pragma unroll
      for (int n=0;n<2;n++)
        #pragma unroll
        for (int r=0;r<4;r++){
          int row = (half*2 + i)*16 + lg*4 + r;
          int col = hd*32 + n*16 + lr;
          Clds[row*192 + (((col>>3) ^ (row&7)) << 3) + (col & 7)] = f2bf(oa[i][n][r]);
        }
    __syncthreads();               // ctx complete

    // prefetch residual x values (hide global latency under proj MFMAs)
    float rx[2][2][4];
    #pragma unroll
    for (int i=0;i<2;i++)
      #pragma unroll
      for (int n=0;n<2;n++){
        int col = hd*32 + n*16 + lr;
        #pragma unroll
        for (int r=0;r<4;r++){
          int rowl = half*32 + i*16 + lg*4 + r;
          rx[i][n][r] = x[(size_t)tok2glob(widx*64 + rowl)*192 + col];
        }
      }

    // ---- proj + residual scatter; wave does rows [half*32,+32), cols [hd*32,+32) ----
    f32x4 pacc[2][2];
    #pragma unroll
    for (int i=0;i<2;i++)
      #pragma unroll
      for (int n=0;n<2;n++) pacc[i][n] = zero;
    #pragma unroll
    for (int kk = 0; kk < 6; kk++){
      bhalf8 af[2];
      #pragma unroll
      for (int i = 0; i < 2; i++){
        int row = half*32 + i*16 + lr;
        af[i] = *(const bhalf8*)&Clds[row*192 + (((kk*4 + lg) ^ (row & 7)) << 3)];
      }
      __builtin_amdgcn_s_setprio(1);
      #pragma unroll
      for (int i=0;i<2;i++)
        #pragma unroll
        for (int n=0;n<2;n++)
          pacc[i][n] = __builtin_amdgcn_mfma_f32_16x16x32_bf16(af[i], pw[kk][n], pacc[i][n], 0, 0, 0);
      __builtin_amdgcn_s_setprio(0);
    }
    #pragma unroll
    for (int i=0;i<2;i++)
      #pragma unroll
      for (int n=0;n<2;n++){
        int col = hd*32 + n*16 + lr;
        float bv = proj_b[col];
        #pragma unroll
        for (int r=0;r<4;r++){
          int rowl = half*32 + i*16 + lg*4 + r;
          int g = tok2glob(widx*64 + rowl);
          out[(size_t)g*192 + col] = rx[i][n][r] + bv + pacc[i][n][r];
        }
      }
    __syncthreads();               // protect AsB/QKB reuse by next window
  }
}

// =================== fc1 (+fused LN2): 256 tokens/block, 8 waves x 32 tokens ===================
__global__ __launch_bounds__(512, 4) void fc1_kernel(const float* __restrict__ X,
    const float* __restrict__ n2g, const float* __restrict__ n2b,
    const u16* __restrict__ Bt, const float* __restrict__ bias, u16* __restrict__ H1){
  __shared__ u16 Wl[2][64*192];               // 24 KB each, granule-swizzled
  int tid = threadIdx.x;
  int mBase = blockIdx.x << 8;                // 256 tokens
  int lane = tid & 63, w = tid >> 6;
  int lr = lane & 15, lg = lane >> 4;
  int tokBase = mBase + (w << 5);             // wave's 32 tokens

  bhalf8 tF[2][6];
  #pragma unroll
  for (int i = 0; i < 2; i++){
    const float* xr = X + (size_t)(tokBase + i*16 + lr)*192;
    float4 va[12];                            // this thread's 48 channels of the row
    float s = 0.f, sq = 0.f;
    #pragma unroll
    for (int kk = 0; kk < 6; kk++){
      float4 a = *(const float4*)(xr + kk*32 + (lg<<3));
      float4 b = *(const float4*)(xr + kk*32 + (lg<<3) + 4);
      va[2*kk] = a; va[2*kk+1] = b;
      s  += a.x+a.y+a.z+a.w + b.x+b.y+b.z+b.w;
      sq += a.x*a.x+a.y*a.y+a.z*a.z+a.w*a.w + b.x*b.x+b.y*b.y+b.z*b.z+b.w*b.w;
    }
    s  += __shfl_xor(s, 16, 64);  sq += __shfl_xor(sq, 16, 64);
    s  += __shfl_xor(s, 32, 64);  sq += __shfl_xor(sq, 32, 64);
    float mean = s * (1.f/192.f);
    float rstd = rsqrtf(sq * (1.f/192.f) - mean*mean + 1e-5f);
    #pragma unroll
    for (int kk = 0; kk < 6; kk++){
      const float* gp = n2g + kk*32 + (lg<<3);
      const float* bp = n2b + kk*32 + (lg<<3);
      float4 g0 = *(const float4*)gp, g1 = *(const float4*)(gp+4);
      float4 b0 = *(const float4*)bp, b1 = *(const float4*)(bp+4);
      float4 v0 = va[2*kk], v1 = va[2*kk+1];
      union { bhalf8 h; u32 u[4]; } pk;
      pk.u[0] = f2bf2((v0.x-mean)*rstd*g0.x+b0.x, (v0.y-mean)*rstd*g0.y+b0.y);
      pk.u[1] = f2bf2((v0.z-mean)*rstd*g0.z+b0.z, (v0.w-mean)*rstd*g0.w+b0.w);
      pk.u[2] = f2bf2((v1.x-mean)*rstd*g1.x+b1.x, (v1.y-mean)*rstd*g1.y+b1.y);
      pk.u[3] = f2bf2((v1.z-mean)*rstd*g1.z+b1.z, (v1.w-mean)*rstd*g1.w+b1.w);
      tF[i][kk] = pk.h;
    }
  }

  int scol = tid >> 3, sg0 = (tid & 7) * 3;
  #define STAGE_FC1(nt, buf) { \
    const u16* sp = Bt + (size_t)((nt)*64 + scol)*192 + sg0*8; \
    _Pragma("unroll") \
    for (int j = 0; j < 3; j++){ \
      uint4 v = *(const uint4*)(sp + j*8); \
      *(uint4*)&Wl[buf][scol*192 + (((sg0 + j) ^ (scol & 7)) << 3)] = v; \
    } }

  STAGE_FC1(0, 0)
  for (int nt = 0; nt < 12; nt++){
    __syncthreads();
    if (nt < 11) STAGE_FC1(nt + 1, (nt + 1) & 1)
    int buf = nt & 1;
    #pragma unroll
    for (int cf = 0; cf < 4; cf++){
      bhalf8 wF[6];
      int col = cf*16 + lr;
      #pragma unroll
      for (int kk = 0; kk < 6; kk++)
        wF[kk] = *(const bhalf8*)&Wl[buf][col*192 + (((kk*4 + lg) ^ (col & 7)) << 3)];
      int gcol = (nt << 6) + cf*16;
      float4 bv = *(const float4*)&bias[gcol + (lg<<2)];
      #pragma unroll
      for (int i = 0; i < 2; i++){
        f32x4 a0 = (f32x4){0.f,0.f,0.f,0.f}, a1 = (f32x4){0.f,0.f,0.f,0.f};
        #pragma unroll
        for (int kk = 0; kk < 3; kk++){
          a0 = __builtin_amdgcn_mfma_f32_16x16x32_bf16(wF[2*kk],   tF[i][2*kk],   a0, 0, 0, 0);
          a1 = __builtin_amdgcn_mfma_f32_16x16x32_bf16(wF[2*kk+1], tF[i][2*kk+1], a1, 0, 0, 0);
        }
        float v0 = fast_gelu(a0[0]+a1[0]+bv.x);
        float v1 = fast_gelu(a0[1]+a1[1]+bv.y);
        float v2 = fast_gelu(a0[2]+a1[2]+bv.z);
        float v3 = fast_gelu(a0[3]+a1[3]+bv.w);
        uint2 pk; pk.x = f2bf2(v0, v1); pk.y = f2bf2(v2, v3);
        *(uint2*)&H1[(size_t)(tokBase + i*16 + lr)*768 + gcol + (lg<<2)] = pk;
      }
    }
  }
  #undef STAGE_FC1
}

// =================== fc2: 256 tokens/block, 8 waves, H+W LDS-dbuf, residual RMW ===================
__global__ __launch_bounds__(512, 2) void fc2_kernel(const u16* __restrict__ H1,
    const u16* __restrict__ Bt, const float* __restrict__ bias, float* out){
  __shared__ u16 Hl[2][256*64];               // 32 KB each
  __shared__ u16 Wl[2][192*64];               // 24 KB each
  int tid = threadIdx.x;
  int mBase = blockIdx.x << 8;                // 256 tokens
  int lane = tid & 63, w = tid >> 6;
  int lr = lane & 15, lg = lane >> 4;
  int mq = w >> 1, nh = w & 1;                // wave = 64 tokens x 96 cols

  int srow = tid >> 3, sgk = tid & 7;
  #define STAGE_FC2(p, buf) { \
    _Pragma("unroll") \
    for (int j = 0; j < 4; j++){ \
      int tok = j*64 + srow; \
      uint4 v = *(const uint4*)&H1[(size_t)(mBase + tok)*768 + (p)*64 + sgk*8]; \
      *(uint4*)&Hl[buf][tok*64 + ((sgk ^ (tok & 7)) << 3)] = v; \
    } \
    _Pragma("unroll") \
    for (int j = 0; j < 3; j++){ \
      int col = j*64 + srow; \
      uint4 v = *(const uint4*)&Bt[(size_t)col*768 + (p)*64 + sgk*8]; \
      *(uint4*)&Wl[buf][col*64 + ((sgk ^ (col & 7)) << 3)] = v; \
    } }

  f32x4 acc[4][6];
  #pragma unroll
  for (int i = 0; i < 4; i++)
    #pragma unroll
    for (int cf = 0; cf < 6; cf++) acc[i][cf] = (f32x4){0.f,0.f,0.f,0.f};

  STAGE_FC2(0, 0)
  for (int p = 0; p < 12; p++){
    __syncthreads();
    if (p < 11) STAGE_FC2(p + 1, (p + 1) & 1)
    int buf = p & 1;
    #pragma unroll
    for (int kk = 0; kk < 2; kk++){
      bhalf8 hF[4], wv[6];
      #pragma unroll
      for (int i = 0; i < 4; i++){
        int tok = mq*64 + i*16 + lr;
        hF[i] = *(const bhalf8*)&Hl[buf][tok*64 + (((kk*4 + lg) ^ (tok & 7)) << 3)];
      }
      #pragma unroll
      for (int cf = 0; cf < 6; cf++){
        int col = nh*96 + cf*16 + lr;
        wv[cf] = *(const bhalf8*)&Wl[buf][col*64 + (((kk*4 + lg) ^ (col & 7)) << 3)];
      }
      #pragma unroll
      for (int i = 0; i < 4; i++)
        #pragma unroll
        for (int cf = 0; cf < 6; cf++)
          acc[i][cf] = __builtin_amdgcn_mfma_f32_16x16x32_bf16(wv[cf], hF[i], acc[i][cf], 0, 0, 0);
    }
  }
  #undef STAGE_FC2

  #pragma unroll
  for (int i = 0; i < 4; i++)
    #pragma unroll
    for (int cf = 0; cf < 6; cf++){
      int col = nh*96 + cf*16 + (lg<<2);
      float4 bv = *(const float4*)&bias[col];
      int row = mBase + mq*64 + i*16 + lr;
      float4* op = (float4*)&out[(size_t)row*192 + col];
      float4 o = *op;
      o.x += bv.x + acc[i][cf][0];
      o.y += bv.y + acc[i][cf][1];
      o.z += bv.z + acc[i][cf][2];
      o.w += bv.w + acc[i][cf][3];
      *op = o;
    }
}

extern "C" void kernel_launch(void* const* d_in, const int* in_sizes, int n_in,
                              void* d_out, int out_size, void* d_ws, size_t ws_size,
                              hipStream_t stream){
  const float* x      = (const float*)d_in[0];
  const float* n1g    = (const float*)d_in[1];
  const float* n1b    = (const float*)d_in[2];
  const float* qkv_w  = (const float*)d_in[3];
  const float* qkv_b  = (const float*)d_in[4];
  const float* proj_w = (const float*)d_in[5];
  const float* proj_b = (const float*)d_in[6];
  const float* rpb    = (const float*)d_in[7];
  const float* n2g    = (const float*)d_in[8];
  const float* n2b    = (const float*)d_in[9];
  const float* fc1_w  = (const float*)d_in[10];
  const float* fc1_b  = (const float*)d_in[11];
  const float* fc2_w  = (const float*)d_in[12];
  const float* fc2_b  = (const float*)d_in[13];
  float* out = (float*)d_out;

  const size_t T = 131072;
  u16* H1     = (u16*)d_ws;            // T*768 bf16
  u16* qkvWt  = H1 + T*768;
  u16* projWt = qkvWt + 576*192;
  u16* fc1Wt  = projWt + 192*192;
  u16* fc2Wt  = fc1Wt + 768*192;

  transcast_all_kernel<<<dim3(1728),256,0,stream>>>(qkv_w, proj_w, fc1_w, fc2_w,
                                                    qkvWt, projWt, fc1Wt, fc2Wt);

  // LN1 + qkv + attention + proj + residual -> out (xmid), 2 windows/block
  attn_fused_kernel<<<dim3(1024),768,0,stream>>>(x, n1g, n1b, qkvWt, qkv_b,
                                                 projWt, proj_b, out, rpb);
  // LN2 + fc1 + GELU -> H1
  fc1_kernel<<<dim3(512),512,0,stream>>>(out, n2g, n2b, fc1Wt, fc1_b, H1);
  // fc2 + residual (RMW on out)
  fc2_kernel<<<dim3(512),512,0,stream>>>(H1, fc2Wt, fc2_b, out);
}

// Round 21
// 352.082 us; speedup vs baseline: 2.0464x; 2.0464x over previous
//
#include <hip/hip_runtime.h>
#include <hip/hip_bf16.h>

// Swin block, MI355X. v21 FINAL: exact v19/v17 restore (353us, thrice-measured).
// attn: LN1+qkv+attn+proj+residual fused, 1 block/window, 12 waves.
// fc1: LN2 fused, 256-tok blocks, W LDS-dbuf. fc2: 256-tok, H+W LDS-dbuf.
// B=32 H=W=64 C=192 WS=8 SS=4 NH=6 Dh=32; T=131072.

#define DI __device__ __forceinline__

typedef __attribute__((ext_vector_type(8))) short bhalf8;   // 8 bf16 (4 VGPR)
typedef __attribute__((ext_vector_type(4))) float f32x4;
typedef unsigned short u16;
typedef unsigned int   u32;

DI u32 f2bf2(float a, float b){                // pack 2 f32 -> 2 bf16 (1 VALU op)
  u32 r;
  asm("v_cvt_pk_bf16_f32 %0, %1, %2" : "=v"(r) : "v"(a), "v"(b));
  return r;
}
DI u16 f2bf(float f){ return (u16)f2bf2(f, f); }

// gelu ~= x * sigmoid(1.702 x)
DI float fast_gelu(float x){
  float s = __expf(-1.702f * x);
  return x * __builtin_amdgcn_rcpf(1.0f + s);
}

// window-token index t -> global token g (shift+partition map; gather & scatter identical)
DI int tok2glob(int t){
  int n = t & 63, widx = t >> 6;
  int b = widx >> 6, wi = widx & 63;
  int hh = ((wi >> 3) << 3) + (n >> 3);
  int ww = ((wi & 7) << 3) + (n & 7);
  int hs = (hh + 4) & 63, wsv = (ww + 4) & 63;
  return (b << 12) + (hs << 6) + wsv;
}

DI int region_id(int hpos, int wpos){
  int rh = (hpos < 56) ? 0 : ((hpos < 60) ? 1 : 2);
  int rw = (wpos < 56) ? 0 : ((wpos < 60) ? 1 : 2);
  return rh*3 + rw;
}

// ------------- weight prep, all four in one launch -------------
__global__ void transcast_all_kernel(const float* __restrict__ qw, const float* __restrict__ pw,
    const float* __restrict__ f1, const float* __restrict__ f2,
    u16* __restrict__ o0, u16* __restrict__ o1, u16* __restrict__ o2, u16* __restrict__ o3){
  int idx = blockIdx.x * 256 + threadIdx.x;
  const float* W; u16* O; int K, N;
  if (idx < 110592){ W = qw; O = o0; K = 192; N = 576; }
  else if (idx < 147456){ idx -= 110592; W = pw; O = o1; K = 192; N = 192; }
  else if (idx < 294912){ idx -= 147456; W = f1; O = o2; K = 192; N = 768; }
  else if (idx < 442368){ idx -= 294912; W = f2; O = o3; K = 768; N = 192; }
  else return;
  int n = idx / K, k = idx - n*K;
  O[idx] = f2bf(W[(size_t)k * N + n]);
}

// =================== attn_fused: 1 block / window, 768 threads (12 waves) ===================
__global__ __launch_bounds__(768, 3) void attn_fused_kernel(
    const float* __restrict__ x, const float* __restrict__ n1g, const float* __restrict__ n1b,
    const u16* __restrict__ qkvWt, const float* __restrict__ qkv_b,
    const u16* __restrict__ projWt, const float* __restrict__ proj_b,
    float* __restrict__ out, const float* __restrict__ rpb){
  __shared__ u16 AsB[64*192];      // 24 KB: LN'd tokens; later aliased as Clds
  __shared__ u16 QKB[64*384];      // 48 KB: Q|K tiles; later aliased as P (6 x 64x64)
  __shared__ u16 Vt[6][32*64];     // 24 KB: V^T per head, XOR-swizzled
  __shared__ float Rlds[225*6];
  int widx = blockIdx.x;
  int tid  = threadIdx.x;
  int w = tid >> 6, lane = tid & 63, lr = lane & 15, lg = lane >> 4;

  if (w >= 8){                     // waves 8-11: stage rel-pos bias
    for (int i = tid - 512; i < 225*6; i += 256) Rlds[i] = rpb[i];
  } else {                         // waves 0-7: LN1, 8 threads/row
    int qrow = tid >> 3, oct = tid & 7;
    int g = tok2glob(widx*64 + qrow);
    const float4* xr = (const float4*)(x + (size_t)g*192 + oct*24);
    float4 va[6];
    float s = 0.f, sq = 0.f;
    #pragma unroll
    for (int j = 0; j < 6; j++){
      va[j] = xr[j];
      s  += va[j].x + va[j].y + va[j].z + va[j].w;
      sq += va[j].x*va[j].x + va[j].y*va[j].y + va[j].z*va[j].z + va[j].w*va[j].w;
    }
    s  += __shfl_xor(s, 1, 64);  sq += __shfl_xor(sq, 1, 64);
    s  += __shfl_xor(s, 2, 64);  sq += __shfl_xor(sq, 2, 64);
    s  += __shfl_xor(s, 4, 64);  sq += __shfl_xor(sq, 4, 64);
    float mean = s * (1.f/192.f);
    float rstd = rsqrtf(sq * (1.f/192.f) - mean*mean + 1e-5f);
    const float4* g4 = (const float4*)(n1g + oct*24);
    const float4* b4 = (const float4*)(n1b + oct*24);
    #pragma unroll
    for (int j2 = 0; j2 < 3; j2++){
      float4 v0 = va[2*j2], v1 = va[2*j2+1];
      float4 g0 = g4[2*j2], g1 = g4[2*j2+1];
      float4 b0 = b4[2*j2], b1 = b4[2*j2+1];
      uint4 pk;
      pk.x = f2bf2((v0.x-mean)*rstd*g0.x+b0.x, (v0.y-mean)*rstd*g0.y+b0.y);
      pk.y = f2bf2((v0.z-mean)*rstd*g0.z+b0.z, (v0.w-mean)*rstd*g0.w+b0.w);
      pk.z = f2bf2((v1.x-mean)*rstd*g1.x+b1.x, (v1.y-mean)*rstd*g1.y+b1.y);
      pk.w = f2bf2((v1.z-mean)*rstd*g1.z+b1.z, (v1.w-mean)*rstd*g1.w+b1.w);
      int gk = oct*3 + j2;
      *(uint4*)&AsB[qrow*192 + ((gk ^ (qrow & 7)) << 3)] = pk;
    }
  }
  __syncthreads();                 // AsB + Rlds ready

  // ---- qkv GEMM: wave w computes output cols [w*48, w*48+48) ----
  #pragma unroll
  for (int nf = 0; nf < 3; nf++){
    int cBase = w*48 + nf*16;
    bhalf8 wF[6];
    #pragma unroll
    for (int kk = 0; kk < 6; kk++)
      wF[kk] = *(const bhalf8*)&qkvWt[(size_t)(cBase + lr)*192 + kk*32 + (lg<<3)];
    float4 bv = *(const float4*)&qkv_b[cBase + (lg<<2)];
    #pragma unroll
    for (int i = 0; i < 4; i++){
      f32x4 a0 = (f32x4){0.f,0.f,0.f,0.f}, a1 = (f32x4){0.f,0.f,0.f,0.f};
      #pragma unroll
      for (int kk = 0; kk < 3; kk++){
        int row = i*16 + lr;
        bhalf8 t0 = *(const bhalf8*)&AsB[row*192 + (((2*kk*4     + lg) ^ (row & 7)) << 3)];
        bhalf8 t1 = *(const bhalf8*)&AsB[row*192 + ((((2*kk+1)*4 + lg) ^ (row & 7)) << 3)];
        a0 = __builtin_amdgcn_mfma_f32_16x16x32_bf16(wF[2*kk],   t0, a0, 0, 0, 0);
        a1 = __builtin_amdgcn_mfma_f32_16x16x32_bf16(wF[2*kk+1], t1, a1, 0, 0, 0);
      }
      float v0 = a0[0]+a1[0]+bv.x, v1 = a0[1]+a1[1]+bv.y;
      float v2 = a0[2]+a1[2]+bv.z, v3 = a0[3]+a1[3]+bv.w;
      int token = i*16 + lr;
      if (cBase < 384){            // Q|K: packed uint2 into swizzled QKB
        int gq = (cBase >> 3) + (lg >> 1);
        uint2 pk; pk.x = f2bf2(v0, v1); pk.y = f2bf2(v2, v3);
        *(uint2*)&QKB[token*384 + ((gq ^ (token & 7)) << 3) + ((lg & 1) << 2)] = pk;
      } else {                     // V: transposed scatter into Vt
        int d0 = cBase + (lg<<2) - 384;
        int hv = d0 >> 5;
        int db = d0 & 31;
        Vt[hv][(db+0)*64 + (token ^ (((db+0)&7)<<3))] = f2bf(v0);
        Vt[hv][(db+1)*64 + (token ^ (((db+1)&7)<<3))] = f2bf(v1);
        Vt[hv][(db+2)*64 + (token ^ (((db+2)&7)<<3))] = f2bf(v2);
        Vt[hv][(db+3)*64 + (token ^ (((db+3)&7)<<3))] = f2bf(v3);
      }
    }
  }
  __syncthreads();                 // QKB + Vt complete

  // ---- scores: wave (hd, half) = head hd, q-rows [half*32, half*32+32) ----
  int hd   = (w < 6) ? w : (w - 6);
  int half = (w < 6) ? 0 : 1;
  bhalf8 qf[2], kf[4];
  #pragma unroll
  for (int i = 0; i < 2; i++){
    int token = (half*2 + i)*16 + lr;
    int gq = hd*4 + lg;
    qf[i] = *(const bhalf8*)&QKB[token*384 + ((gq ^ (token & 7)) << 3)];
  }
  #pragma unroll
  for (int j = 0; j < 4; j++){
    int token = j*16 + lr;
    int gk = 24 + hd*4 + lg;
    kf[j] = *(const bhalf8*)&QKB[token*384 + ((gk ^ (token & 7)) << 3)];
  }
  f32x4 sc[2][4];
  f32x4 zero = (f32x4){0.f,0.f,0.f,0.f};
  __builtin_amdgcn_s_setprio(1);
  #pragma unroll
  for (int i = 0; i < 2; i++)
    #pragma unroll
    for (int j = 0; j < 4; j++)
      sc[i][j] = __builtin_amdgcn_mfma_f32_16x16x32_bf16(qf[i], kf[j], zero, 0, 0, 0);
  __builtin_amdgcn_s_setprio(0);

  // prefetch proj weight fragments (used after PV; loads hide under softmax+PV)
  bhalf8 pw[6][2];
  #pragma unroll
  for (int kk = 0; kk < 6; kk++)
    #pragma unroll
    for (int n = 0; n < 2; n++)
      pw[kk][n] = *(const bhalf8*)&projWt[(size_t)(hd*32 + n*16 + lr)*192 + kk*32 + (lg<<3)];

  __syncthreads();                 // all QKB reads done -> safe to overwrite with P

  // ---- softmax (+rel-pos bias +shift mask), P into QKB region ----
  u16* Plds = &QKB[0];
  int mwin = widx >> 5;            // faithful to reference reshape quirk
  int mh0 = (mwin >> 3) << 3, mw0 = (mwin & 7) << 3;
  #pragma unroll
  for (int i = 0; i < 2; i++){
    #pragma unroll
    for (int r = 0; r < 4; r++){
      int row = (half*2 + i)*16 + lg*4 + r;
      int ih = row >> 3, iw = row & 7;
      int ridr = region_id(mh0 + ih, mw0 + iw);
      float vals[4];
      #pragma unroll
      for (int j = 0; j < 4; j++){
        int col = j*16 + lr;
        int jh = col >> 3, jw = col & 7;
        float bias = Rlds[((ih-jh+7)*15 + (iw-jw+7))*6 + hd];
        int ridc = region_id(mh0 + jh, mw0 + jw);
        vals[j] = sc[i][j][r] * 0.17677669529663687f + bias + ((ridr==ridc) ? 0.f : -100.f);
      }
      float mx = fmaxf(fmaxf(vals[0],vals[1]), fmaxf(vals[2],vals[3]));
      #pragma unroll
      for (int d = 1; d < 16; d <<= 1) mx = fmaxf(mx, __shfl_xor(mx, d, 64));
      float sum = 0.f;
      #pragma unroll
      for (int j = 0; j < 4; j++){ vals[j] = __expf(vals[j]-mx); sum += vals[j]; }
      #pragma unroll
      for (int d = 1; d < 16; d <<= 1) sum += __shfl_xor(sum, d, 64);
      float inv = __builtin_amdgcn_rcpf(sum);
      #pragma unroll
      for (int j = 0; j < 4; j++){
        int col = j*16 + lr;
        Plds[hd*4096 + row*64 + (col ^ ((row & 7) << 3))] = f2bf(vals[j]*inv);
      }
    }
  }

  // ---- PV: wave-local P rows + Vt[hd] ----
  f32x4 oa[2][2];
  #pragma unroll
  for (int i=0;i<2;i++)
    #pragma unroll
    for (int n=0;n<2;n++) oa[i][n] = zero;
  #pragma unroll
  for (int kb = 0; kb < 2; kb++){
    bhalf8 pf[2], vf[2];
    int k = (kb<<5) + (lg<<3);
    #pragma unroll
    for (int i = 0; i < 2; i++){
      int row = (half*2 + i)*16 + lr;
      pf[i] = *(const bhalf8*)&Plds[hd*4096 + row*64 + (k ^ ((row&7)<<3))];
    }
    #pragma unroll
    for (int n = 0; n < 2; n++){
      int d = n*16 + lr;
      vf[n] = *(const bhalf8*)&Vt[hd][d*64 + (k ^ ((d&7)<<3))];
    }
    __builtin_amdgcn_s_setprio(1);
    #pragma unroll
    for (int i=0;i<2;i++)
      #pragma unroll
      for (int n=0;n<2;n++)
        oa[i][n] = __builtin_amdgcn_mfma_f32_16x16x32_bf16(pf[i], vf[n], oa[i][n], 0, 0, 0);
    __builtin_amdgcn_s_setprio(0);
  }

  // ---- ctx -> Clds (aliases AsB; AsB dead since qkv barrier) ----
  u16* Clds = &AsB[0];
  #pragma unroll
  for (int i=0;i<2;i++)
    #pragma unroll
    for (int n=0;n<2;n++)
      #pragma unroll
      for (int r=0;r<4;r++){
        int row = (half*2 + i)*16 + lg*4 + r;
        int col = hd*32 + n*16 + lr;
        Clds[row*192 + (((col>>3) ^ (row&7)) << 3) + (col & 7)] = f2bf(oa[i][n][r]);
      }
  __syncthreads();                 // ctx complete

  // prefetch residual x values (hide global latency under proj MFMAs)
  float rx[2][2][4];
  #pragma unroll
  for (int i=0;i<2;i++)
    #pragma unroll
    for (int n=0;n<2;n++){
      int col = hd*32 + n*16 + lr;
      #pragma unroll
      for (int r=0;r<4;r++){
        int rowl = half*32 + i*16 + lg*4 + r;
        rx[i][n][r] = x[(size_t)tok2glob(widx*64 + rowl)*192 + col];
      }
    }

  // ---- proj + residual scatter; wave does rows [half*32,+32), cols [hd*32,+32) ----
  f32x4 pacc[2][2];
  #pragma unroll
  for (int i=0;i<2;i++)
    #pragma unroll
    for (int n=0;n<2;n++) pacc[i][n] = zero;
  #pragma unroll
  for (int kk = 0; kk < 6; kk++){
    bhalf8 af[2];
    #pragma unroll
    for (int i = 0; i < 2; i++){
      int row = half*32 + i*16 + lr;
      af[i] = *(const bhalf8*)&Clds[row*192 + (((kk*4 + lg) ^ (row & 7)) << 3)];
    }
    __builtin_amdgcn_s_setprio(1);
    #pragma unroll
    for (int i=0;i<2;i++)
      #pragma unroll
      for (int n=0;n<2;n++)
        pacc[i][n] = __builtin_amdgcn_mfma_f32_16x16x32_bf16(af[i], pw[kk][n], pacc[i][n], 0, 0, 0);
    __builtin_amdgcn_s_setprio(0);
  }
  #pragma unroll
  for (int i=0;i<2;i++)
    #pragma unroll
    for (int n=0;n<2;n++){
      int col = hd*32 + n*16 + lr;
      float bv = proj_b[col];
      #pragma unroll
      for (int r=0;r<4;r++){
        int rowl = half*32 + i*16 + lg*4 + r;
        int g = tok2glob(widx*64 + rowl);
        out[(size_t)g*192 + col] = rx[i][n][r] + bv + pacc[i][n][r];
      }
    }
}

// =================== fc1 (+fused LN2): 256 tokens/block, 8 waves x 32 tokens ===================
__global__ __launch_bounds__(512, 4) void fc1_kernel(const float* __restrict__ X,
    const float* __restrict__ n2g, const float* __restrict__ n2b,
    const u16* __restrict__ Bt, const float* __restrict__ bias, u16* __restrict__ H1){
  __shared__ u16 Wl[2][64*192];               // 24 KB each, granule-swizzled
  int tid = threadIdx.x;
  int mBase = blockIdx.x << 8;                // 256 tokens
  int lane = tid & 63, w = tid >> 6;
  int lr = lane & 15, lg = lane >> 4;
  int tokBase = mBase + (w << 5);             // wave's 32 tokens

  bhalf8 tF[2][6];
  #pragma unroll
  for (int i = 0; i < 2; i++){
    const float* xr = X + (size_t)(tokBase + i*16 + lr)*192;
    float4 va[12];                            // this thread's 48 channels of the row
    float s = 0.f, sq = 0.f;
    #pragma unroll
    for (int kk = 0; kk < 6; kk++){
      float4 a = *(const float4*)(xr + kk*32 + (lg<<3));
      float4 b = *(const float4*)(xr + kk*32 + (lg<<3) + 4);
      va[2*kk] = a; va[2*kk+1] = b;
      s  += a.x+a.y+a.z+a.w + b.x+b.y+b.z+b.w;
      sq += a.x*a.x+a.y*a.y+a.z*a.z+a.w*a.w + b.x*b.x+b.y*b.y+b.z*b.z+b.w*b.w;
    }
    s  += __shfl_xor(s, 16, 64);  sq += __shfl_xor(sq, 16, 64);
    s  += __shfl_xor(s, 32, 64);  sq += __shfl_xor(sq, 32, 64);
    float mean = s * (1.f/192.f);
    float rstd = rsqrtf(sq * (1.f/192.f) - mean*mean + 1e-5f);
    #pragma unroll
    for (int kk = 0; kk < 6; kk++){
      const float* gp = n2g + kk*32 + (lg<<3);
      const float* bp = n2b + kk*32 + (lg<<3);
      float4 g0 = *(const float4*)gp, g1 = *(const float4*)(gp+4);
      float4 b0 = *(const float4*)bp, b1 = *(const float4*)(bp+4);
      float4 v0 = va[2*kk], v1 = va[2*kk+1];
      union { bhalf8 h; u32 u[4]; } pk;
      pk.u[0] = f2bf2((v0.x-mean)*rstd*g0.x+b0.x, (v0.y-mean)*rstd*g0.y+b0.y);
      pk.u[1] = f2bf2((v0.z-mean)*rstd*g0.z+b0.z, (v0.w-mean)*rstd*g0.w+b0.w);
      pk.u[2] = f2bf2((v1.x-mean)*rstd*g1.x+b1.x, (v1.y-mean)*rstd*g1.y+b1.y);
      pk.u[3] = f2bf2((v1.z-mean)*rstd*g1.z+b1.z, (v1.w-mean)*rstd*g1.w+b1.w);
      tF[i][kk] = pk.h;
    }
  }

  int scol = tid >> 3, sg0 = (tid & 7) * 3;
  #define STAGE_FC1(nt, buf) { \
    const u16* sp = Bt + (size_t)((nt)*64 + scol)*192 + sg0*8; \
    _Pragma("unroll") \
    for (int j = 0; j < 3; j++){ \
      uint4 v = *(const uint4*)(sp + j*8); \
      *(uint4*)&Wl[buf][scol*192 + (((sg0 + j) ^ (scol & 7)) << 3)] = v; \
    } }

  STAGE_FC1(0, 0)
  for (int nt = 0; nt < 12; nt++){
    __syncthreads();
    if (nt < 11) STAGE_FC1(nt + 1, (nt + 1) & 1)
    int buf = nt & 1;
    #pragma unroll
    for (int cf = 0; cf < 4; cf++){
      bhalf8 wF[6];
      int col = cf*16 + lr;
      #pragma unroll
      for (int kk = 0; kk < 6; kk++)
        wF[kk] = *(const bhalf8*)&Wl[buf][col*192 + (((kk*4 + lg) ^ (col & 7)) << 3)];
      int gcol = (nt << 6) + cf*16;
      float4 bv = *(const float4*)&bias[gcol + (lg<<2)];
      #pragma unroll
      for (int i = 0; i < 2; i++){
        f32x4 a0 = (f32x4){0.f,0.f,0.f,0.f}, a1 = (f32x4){0.f,0.f,0.f,0.f};
        #pragma unroll
        for (int kk = 0; kk < 3; kk++){
          a0 = __builtin_amdgcn_mfma_f32_16x16x32_bf16(wF[2*kk],   tF[i][2*kk],   a0, 0, 0, 0);
          a1 = __builtin_amdgcn_mfma_f32_16x16x32_bf16(wF[2*kk+1], tF[i][2*kk+1], a1, 0, 0, 0);
        }
        float v0 = fast_gelu(a0[0]+a1[0]+bv.x);
        float v1 = fast_gelu(a0[1]+a1[1]+bv.y);
        float v2 = fast_gelu(a0[2]+a1[2]+bv.z);
        float v3 = fast_gelu(a0[3]+a1[3]+bv.w);
        uint2 pk; pk.x = f2bf2(v0, v1); pk.y = f2bf2(v2, v3);
        *(uint2*)&H1[(size_t)(tokBase + i*16 + lr)*768 + gcol + (lg<<2)] = pk;
      }
    }
  }
  #undef STAGE_FC1
}

// =================== fc2: 256 tokens/block, 8 waves, H+W LDS-dbuf, residual RMW ===================
__global__ __launch_bounds__(512, 2) void fc2_kernel(const u16* __restrict__ H1,
    const u16* __restrict__ Bt, const float* __restrict__ bias, float* out){
  __shared__ u16 Hl[2][256*64];               // 32 KB each
  __shared__ u16 Wl[2][192*64];               // 24 KB each
  int tid = threadIdx.x;
  int mBase = blockIdx.x << 8;                // 256 tokens
  int lane = tid & 63, w = tid >> 6;
  int lr = lane & 15, lg = lane >> 4;
  int mq = w >> 1, nh = w & 1;                // wave = 64 tokens x 96 cols

  int srow = tid >> 3, sgk = tid & 7;
  #define STAGE_FC2(p, buf) { \
    _Pragma("unroll") \
    for (int j = 0; j < 4; j++){ \
      int tok = j*64 + srow; \
      uint4 v = *(const uint4*)&H1[(size_t)(mBase + tok)*768 + (p)*64 + sgk*8]; \
      *(uint4*)&Hl[buf][tok*64 + ((sgk ^ (tok & 7)) << 3)] = v; \
    } \
    _Pragma("unroll") \
    for (int j = 0; j < 3; j++){ \
      int col = j*64 + srow; \
      uint4 v = *(const uint4*)&Bt[(size_t)col*768 + (p)*64 + sgk*8]; \
      *(uint4*)&Wl[buf][col*64 + ((sgk ^ (col & 7)) << 3)] = v; \
    } }

  f32x4 acc[4][6];
  #pragma unroll
  for (int i = 0; i < 4; i++)
    #pragma unroll
    for (int cf = 0; cf < 6; cf++) acc[i][cf] = (f32x4){0.f,0.f,0.f,0.f};

  STAGE_FC2(0, 0)
  for (int p = 0; p < 12; p++){
    __syncthreads();
    if (p < 11) STAGE_FC2(p + 1, (p + 1) & 1)
    int buf = p & 1;
    #pragma unroll
    for (int kk = 0; kk < 2; kk++){
      bhalf8 hF[4], wv[6];
      #pragma unroll
      for (int i = 0; i < 4; i++){
        int tok = mq*64 + i*16 + lr;
        hF[i] = *(const bhalf8*)&Hl[buf][tok*64 + (((kk*4 + lg) ^ (tok & 7)) << 3)];
      }
      #pragma unroll
      for (int cf = 0; cf < 6; cf++){
        int col = nh*96 + cf*16 + lr;
        wv[cf] = *(const bhalf8*)&Wl[buf][col*64 + (((kk*4 + lg) ^ (col & 7)) << 3)];
      }
      #pragma unroll
      for (int i = 0; i < 4; i++)
        #pragma unroll
        for (int cf = 0; cf < 6; cf++)
          acc[i][cf] = __builtin_amdgcn_mfma_f32_16x16x32_bf16(wv[cf], hF[i], acc[i][cf], 0, 0, 0);
    }
  }
  #undef STAGE_FC2

  #pragma unroll
  for (int i = 0; i < 4; i++)
    #pragma unroll
    for (int cf = 0; cf < 6; cf++){
      int col = nh*96 + cf*16 + (lg<<2);
      float4 bv = *(const float4*)&bias[col];
      int row = mBase + mq*64 + i*16 + lr;
      float4* op = (float4*)&out[(size_t)row*192 + col];
      float4 o = *op;
      o.x += bv.x + acc[i][cf][0];
      o.y += bv.y + acc[i][cf][1];
      o.z += bv.z + acc[i][cf][2];
      o.w += bv.w + acc[i][cf][3];
      *op = o;
    }
}

extern "C" void kernel_launch(void* const* d_in, const int* in_sizes, int n_in,
                              void* d_out, int out_size, void* d_ws, size_t ws_size,
                              hipStream_t stream){
  const float* x      = (const float*)d_in[0];
  const float* n1g    = (const float*)d_in[1];
  const float* n1b    = (const float*)d_in[2];
  const float* qkv_w  = (const float*)d_in[3];
  const float* qkv_b  = (const float*)d_in[4];
  const float* proj_w = (const float*)d_in[5];
  const float* proj_b = (const float*)d_in[6];
  const float* rpb    = (const float*)d_in[7];
  const float* n2g    = (const float*)d_in[8];
  const float* n2b    = (const float*)d_in[9];
  const float* fc1_w  = (const float*)d_in[10];
  const float* fc1_b  = (const float*)d_in[11];
  const float* fc2_w  = (const float*)d_in[12];
  const float* fc2_b  = (const float*)d_in[13];
  float* out = (float*)d_out;

  const size_t T = 131072;
  u16* H1     = (u16*)d_ws;            // T*768 bf16
  u16* qkvWt  = H1 + T*768;
  u16* projWt = qkvWt + 576*192;
  u16* fc1Wt  = projWt + 192*192;
  u16* fc2Wt  = fc1Wt + 768*192;

  transcast_all_kernel<<<dim3(1728),256,0,stream>>>(qkv_w, proj_w, fc1_w, fc2_w,
                                                    qkvWt, projWt, fc1Wt, fc2Wt);

  // LN1 + qkv + attention + proj + residual -> out (xmid)
  attn_fused_kernel<<<dim3(2048),768,0,stream>>>(x, n1g, n1b, qkvWt, qkv_b,
                                                 projWt, proj_b, out, rpb);
  // LN2 + fc1 + GELU -> H1
  fc1_kernel<<<dim3(512),512,0,stream>>>(out, n2g, n2b, fc1Wt, fc1_b, H1);
  // fc2 + residual (RMW on out)
  fc2_kernel<<<dim3(512),512,0,stream>>>(H1, fc2Wt, fc2_b, out);
}